// Round 6
// baseline (127.487 us; speedup 1.0000x reference)
//
#include <hip/hip_runtime.h>

// Problem constants (B=2, C=256, H=W=48, d_model=256, 8 heads, d_k=32)
// Inputs/outputs fp32. Internals bf16; all matmuls + attention on MFMA.
// R21 = R17 (last fully-passing, 126.09us) with attn/out reverted verbatim;
// QW=3 restructure ABANDONED (R18 NaN = cvtpk asm; R19 replay-divergence =
// QW=3 structure, mechanism unidentified -> reverted).
// Single change vs R17: qkv x-staging uses float4 loads + packed b32 LDS
// writes (16 loads vs 64 scalar per thread), f2bf RNE -> bit-identical.
// Compact 475-tile bias table; bias as S-MFMA C-in; exp2 domain; ones-MFMA
// row sums; software-pipelined eb loads; setprio. 3 dispatches.
#define HW 2304
#define SW 48
#define DMODEL 256
#define NHEADS 8
#define DK 32
#define BATCH 2

typedef unsigned short u16;
typedef __attribute__((ext_vector_type(8))) short short8;
typedef __attribute__((ext_vector_type(4))) float f32x4;

__device__ __forceinline__ float bf2f(u16 v) {
  union { unsigned int u; float f; } c; c.u = ((unsigned int)v) << 16; return c.f;
}
__device__ __forceinline__ float lo2f(unsigned int u) {
  union { unsigned int u; float f; } c; c.u = u << 16; return c.f;
}
__device__ __forceinline__ float hi2f(unsigned int u) {
  union { unsigned int u; float f; } c; c.u = u & 0xffff0000u; return c.f;
}
__device__ __forceinline__ u16 f2bf(float f) {
  union { unsigned int u; float f; } c; c.f = f;
  unsigned int u = c.u;
  unsigned int r = (u + 0x7FFFu + ((u >> 16) & 1u)) >> 16;
  return (u16)r;
}
// pack two floats -> two bf16 (TRUNCATION) in one v_perm_b32
__device__ __forceinline__ unsigned int pkbf(float a, float b) {
  union { float f; unsigned int u; } ca, cb;
  ca.f = a; cb.f = b;
  return __builtin_amdgcn_perm(ca.u, cb.u, 0x03020706u);
}
// native exp2 (P = exp2(S') with S' pre-scaled by log2 e == exp(S))
__device__ __forceinline__ float ex2(float x) {
#if __has_builtin(__builtin_amdgcn_exp2f)
  return __builtin_amdgcn_exp2f(x);
#else
  return __expf(x * 0.6931471805599453f);
#endif
}
// exact floor(n/48) for n in [0, 2304): magic 87382 = (2^22+32)/48
__device__ __forceinline__ int div48(int n) { return (n * 87382) >> 22; }
// exact floor(n/3) for n < 512
__device__ __forceinline__ int div3(int n) { return (n * 171) >> 9; }
// fragment-order swizzle for a [rows][256] bf16 matrix
__device__ __forceinline__ int swz(int row, int k) {
  return ((row >> 4) << 12) + ((k >> 3) << 7) + ((row & 15) << 3) + (k & 7);
}
// A-fragment (16x16x32 bf16, lane = lo + 16*quad) built inline from a fp32
// row pointer already offset to [row][quad*8]: 8 consecutive fp32 -> 8 bf16.
__device__ __forceinline__ short8 ldA8(const float* p) {
  float4 a = *(const float4*)(p);
  float4 c = *(const float4*)(p + 4);
  u16 o[8];
  o[0] = f2bf(a.x); o[1] = f2bf(a.y); o[2] = f2bf(a.z); o[3] = f2bf(a.w);
  o[4] = f2bf(c.x); o[5] = f2bf(c.y); o[6] = f2bf(c.z); o[7] = f2bf(c.w);
  return *(const short8*)o;
}

#define LOG2E 1.4426950408889634f

// ---------------------------------------------------------------------------
// K1: QKV projection (float4 x-transpose staging + inline fp32-W frags)
// plus 60 rider blocks building the compact bias table.
// grid 924 = 864 qkv (36 n-tiles x 12 mb x 2 b) + 60 et. block 256.
__global__ __launch_bounds__(256) void qkv_kernel(
    const float* __restrict__ x,
    const float* __restrict__ Wq, const float* __restrict__ Wk,
    const float* __restrict__ Wv,
    const float* __restrict__ bq, const float* __restrict__ bk,
    const float* __restrict__ bv, const float* __restrict__ lam_p,
    u16* __restrict__ qt, u16* __restrict__ ktb, u16* __restrict__ vb,
    u16* __restrict__ et) {
  int bid = blockIdx.x;
  int t = threadIdx.x;
  if (bid >= 864) {
    // compact bias table: tile = (dy+47)*5 + (pq-pm+2); entry q_local*16+m_local
    int id = (bid - 864) * 256 + t;
    if (id < 15200) {                // 475 tiles * 256 / 8
      int flat = id * 8;
      int tile = flat >> 8;          // 0..474
      int within = flat & 255;
      int a = within >> 4;           // q_local
      int b0 = within & 15;          // m_local base
      int dyi = (tile * 205) >> 10;  // tile/5, exact for tile<1024
      int dp = tile - dyi * 5;       // 0..4
      float dy = (float)(dyi - 47);
      float dy2 = dy * dy;
      int dxb = (dp - 2) * 16 + a - b0;
      float lam = lam_p[0] * LOG2E;
      u16 o[8];
#pragma unroll
      for (int j = 0; j < 8; ++j) {
        float dx = (float)(dxb - j);
        o[j] = f2bf(lam * __expf(-sqrtf(dy2 + dx * dx)));
      }
      *(uint4*)(et + flat) = *(const uint4*)o;
    }
    return;
  }

  int tmp = bid / 36;
  int nb = bid - tmp * 36;
  int mb = tmp % 12;
  int b = tmp / 12;
  int n0 = nb * 64;
  int w = t >> 6, lane = t & 63, lo = lane & 15, quad = lane >> 4;
  int which = mb >> 2;
  int mrel0 = (mb & 3) * 64;

  __shared__ u16 Bt[16384];  // x B-tile [64 n][256 c] bf16, fragment order

  // stage: thread covers channel pair (c, c+1) x 4 n, 8 passes over c.
  // float4 global loads along n (16 lanes x 16B = 256B contiguous); packed
  // b32 LDS writes (c even -> (n,c),(n,c+1) adjacent in swz layout).
  // f2bf RNE -> values bit-identical to the R17 scalar path.
  {
    const float* xb = x + (size_t)b * DMODEL * HW + n0;
    int cpair = (t >> 4) * 2;        // 0,2,..,30
    int nq = (t & 15) * 4;           // n offset 0..60, same 16-row group
#pragma unroll
    for (int p = 0; p < 8; ++p) {
      int c = p * 32 + cpair;
      float4 va = *(const float4*)(xb + (size_t)c * HW + nq);
      float4 vc = *(const float4*)(xb + (size_t)(c + 1) * HW + nq);
      int a0 = swz(nq, c);           // swz(nq+d,c) = a0 + 8*d for d<4
      *(unsigned int*)&Bt[a0 + 0] =
          (unsigned int)f2bf(va.x) | ((unsigned int)f2bf(vc.x) << 16);
      *(unsigned int*)&Bt[a0 + 8] =
          (unsigned int)f2bf(va.y) | ((unsigned int)f2bf(vc.y) << 16);
      *(unsigned int*)&Bt[a0 + 16] =
          (unsigned int)f2bf(va.z) | ((unsigned int)f2bf(vc.z) << 16);
      *(unsigned int*)&Bt[a0 + 24] =
          (unsigned int)f2bf(va.w) | ((unsigned int)f2bf(vc.w) << 16);
    }
  }
  __syncthreads();

  const float* Wsrc = (which == 0) ? Wq : (which == 1) ? Wk : Wv;
  const float* bias = (which == 0) ? bq : (which == 1) ? bk : bv;
  const float* Ar = Wsrc + (size_t)(mrel0 + w * 16 + lo) * DMODEL + quad * 8;

  f32x4 acc[4] = {{0.f, 0.f, 0.f, 0.f}, {0.f, 0.f, 0.f, 0.f},
                  {0.f, 0.f, 0.f, 0.f}, {0.f, 0.f, 0.f, 0.f}};
#pragma unroll
  for (int k0 = 0; k0 < DMODEL; k0 += 32) {
    short8 af = ldA8(Ar + k0);
    int kblk = ((k0 >> 3) + quad) << 7;
#pragma unroll
    for (int nt = 0; nt < 4; ++nt) {
      short8 bf_ = *(const short8*)&Bt[nt * 4096 + kblk + lo * 8];
      acc[nt] = __builtin_amdgcn_mfma_f32_16x16x32_bf16(af, bf_, acc[nt], 0, 0, 0);
    }
  }

  int mbase = mrel0 + w * 16 + quad * 4;
  if (which == 2) {
#pragma unroll
    for (int reg = 0; reg < 4; ++reg) {
      int mrel = mbase + reg;
      float bi = bias[mrel];
      u16* dst = vb + (size_t)(b * DMODEL + mrel) * HW + n0 + lo;
#pragma unroll
      for (int nt = 0; nt < 4; ++nt) dst[nt * 16] = f2bf(acc[nt][reg] + bi);
    }
  } else {
    float sc = (which == 0) ? (0.17677669529663687f * LOG2E) : 1.0f;
    int h = mbase >> 5, d0 = mbase & 31;
    u16* base = ((which == 0) ? qt : ktb) + (size_t)(b * NHEADS + h) * HW * DK;
    float bi[4], dv[4];
    bool usecos[4], usey[4];
#pragma unroll
    for (int reg = 0; reg < 4; ++reg) {
      int mrel = mbase + reg;
      bi[reg] = bias[mrel];
      int oo = mrel & 127;
      dv[reg] = __expf(-0.07195578415606394f * (float)(oo & ~1));
      usecos[reg] = (oo & 1);
      usey[reg] = (mrel >= 128);
    }
#pragma unroll
    for (int nt = 0; nt < 4; ++nt) {
      int n = n0 + nt * 16 + lo;
      int yy = div48(n), xx = n - yy * SW;
      ushort4 ov;
      float vals[4];
#pragma unroll
      for (int reg = 0; reg < 4; ++reg) {
        float tv = (usey[reg] ? (float)yy : (float)xx) * dv[reg];
        float pe = usecos[reg] ? __cosf(tv) : __sinf(tv);
        vals[reg] = (acc[nt][reg] + bi[reg] + pe) * sc;
      }
      ov.x = f2bf(vals[0]); ov.y = f2bf(vals[1]);
      ov.z = f2bf(vals[2]); ov.w = f2bf(vals[3]);
      *(ushort4*)(base + (size_t)n * DK + d0) = ov;
    }
  }
}

// ---------------------------------------------------------------------------
// K2: MFMA flash attention (R17-verified). S^T + register-resident P,
// split-K(4), double-buffered K/V staging, bias as S-MFMA C-in (exp2
// domain), ones-fragment MFMA row sums, software-pipelined bias loads,
// setprio around the compute section. grid (36, 32, 2): y = h*4+kh.
__global__ __launch_bounds__(256) void attn_kernel(
    const u16* __restrict__ qt, const u16* __restrict__ ktb,
    const u16* __restrict__ vb, const u16* __restrict__ et,
    u16* __restrict__ po_o, float* __restrict__ po_l) {
  int t = threadIdx.x;
  int w = t >> 6;
  int lane = t & 63;
  int lo = lane & 15, quad = lane >> 4;
  int n0 = blockIdx.x * 64;
  int h = blockIdx.y >> 2, kh = blockIdx.y & 3;
  int b = blockIdx.z;

  __shared__ u16 Ks[2][64 * 40];  // ping-pong permuted-row K tiles
  __shared__ u16 Vs[2][32 * 72];  // ping-pong V^T tiles [d][m]

  const u16* qtg = qt + (size_t)(b * NHEADS + h) * HW * DK;
  const u16* ktg = ktb + (size_t)(b * NHEADS + h) * HW * DK;
  const u16* vbg = vb + (size_t)(b * DMODEL + h * DK) * HW;

  short8 qf = *(const short8*)(qtg + (size_t)(n0 + w * 16 + lo) * DK + quad * 8);

  // staging source-key for this thread's LDS row (permutation applied here)
  int srow = t >> 2;                 // LDS row 0..63
  int sks = srow >> 5, srr = srow & 31;
  int sv = (srr < 16) ? (8 * (srr >> 2) + (srr & 3))
                      : (8 * ((srr - 16) >> 2) + 4 + ((srr - 16) & 3));
  int skey = sks * 32 + sv;          // key offset within 64-tile
  int sc8 = (t & 3) * 8;
  int vdd = t >> 3, vmo = (t & 7) * 8;

  // compact bias addressing: tile = qcode - (tm + 2*floor(tm/3))
  int tq = (n0 >> 4) + w;
  int qh = quad >> 1;
  int yqt = div3(tq);
  int qcode = tq + 2 * yqt + 237;    // (yq+47)*5 + pq + 2  (minus m-code)
  const u16* etb = et + lo * 16 + (quad & 1) * 8;

  union { unsigned int u[4]; short8 s; } onesu;
  onesu.u[0] = onesu.u[1] = onesu.u[2] = onesu.u[3] = 0x3F803F80u;  // bf16 1.0
  const short8 onesf = onesu.s;

  f32x4 o0 = {0.f, 0.f, 0.f, 0.f}, o1 = {0.f, 0.f, 0.f, 0.f};
  f32x4 lacc = {0.f, 0.f, 0.f, 0.f};

  const int kt0 = kh * 9;

#define EBLOAD(d0_, d1_, tt_)                                            \
  {                                                                      \
    int tmA_ = (tt_);                                                    \
    int tmB_ = tmA_ + 2;                                                 \
    int ymA_ = div3(tmA_), ymB_ = div3(tmB_);                            \
    d0_ = *(const uint4*)(etb + (size_t)(qcode - tmA_ - 2 * ymA_) * 256);\
    d1_ = *(const uint4*)(etb + (size_t)(qcode - tmB_ - 2 * ymB_) * 256);\
  }

  // prologue: stage tile kt0 into buffer 0; bias for i=0
  uint4 ebA, ebB;
  EBLOAD(ebA, ebB, kt0 * 4 + qh);
  uint4 ebAn = ebA, ebBn = ebB;
  {
    int m0 = kt0 * 64;
    *(uint4*)&Ks[0][srow * 40 + sc8] =
        *(const uint4*)(ktg + (size_t)(m0 + skey) * DK + sc8);
    *(uint4*)&Vs[0][vdd * 72 + vmo] =
        *(const uint4*)(vbg + (size_t)vdd * HW + m0 + vmo);
  }
  __syncthreads();

  for (int i = 0; i < 9; ++i) {
    int cur = i & 1;
    // stage tile i+1 into the other buffer (no barrier needed: distinct buf)
    if (i + 1 < 9) {
      int m1 = (kt0 + i + 1) * 64;
      *(uint4*)&Ks[cur ^ 1][srow * 40 + sc8] =
          *(const uint4*)(ktg + (size_t)(m1 + skey) * DK + sc8);
      *(uint4*)&Vs[cur ^ 1][vdd * 72 + vmo] =
          *(const uint4*)(vbg + (size_t)vdd * HW + m1 + vmo);
      // software-pipelined bias loads for i+1 (L2; latency hidden here)
      EBLOAD(ebAn, ebBn, (kt0 + i + 1) * 4 + qh);
    }

    __builtin_amdgcn_s_setprio(1);
#pragma unroll
    for (int ks = 0; ks < 2; ++ks) {
      uint4 ebv = ks ? ebB : ebA;
      // S^T: A = permuted K rows, B = Q, C-in = bias (log2e domain)
      short8 kfA = *(const short8*)&Ks[cur][(ks * 32 + lo) * 40 + quad * 8];
      short8 kfB = *(const short8*)&Ks[cur][(ks * 32 + 16 + lo) * 40 + quad * 8];
      f32x4 zA = {lo2f(ebv.x), hi2f(ebv.x), lo2f(ebv.y), hi2f(ebv.y)};
      f32x4 zB = {lo2f(ebv.z), hi2f(ebv.z), lo2f(ebv.w), hi2f(ebv.w)};
      f32x4 sA = __builtin_amdgcn_mfma_f32_16x16x32_bf16(kfA, qf, zA, 0, 0, 0);
      f32x4 sB = __builtin_amdgcn_mfma_f32_16x16x32_bf16(kfB, qf, zB, 0, 0, 0);
      // P = exp2(S') : lane's m = ks*32 + 8*quad + {0..7}, q = lo
      float p0 = ex2(sA[0]), p1 = ex2(sA[1]), p2 = ex2(sA[2]), p3 = ex2(sA[3]);
      float p4 = ex2(sB[0]), p5 = ex2(sB[1]), p6 = ex2(sB[2]), p7 = ex2(sB[3]);
      // pack into PV B-fragment via v_perm truncation (1 op per 2 values)
      unsigned int pk32[4] = {pkbf(p0, p1), pkbf(p2, p3),
                              pkbf(p4, p5), pkbf(p6, p7)};
      short8 pfrag = *(const short8*)pk32;
      // row-sums: ones-fragment MFMA sums P over all 32 keys (cross-quad too)
      lacc = __builtin_amdgcn_mfma_f32_16x16x32_bf16(onesf, pfrag, lacc, 0, 0, 0);
      // O^T += V^T P^T : A = V^T rows d, B = P (q cols)
      short8 v0 = *(const short8*)&Vs[cur][lo * 72 + ks * 32 + quad * 8];
      o0 = __builtin_amdgcn_mfma_f32_16x16x32_bf16(v0, pfrag, o0, 0, 0, 0);
      short8 v1 = *(const short8*)&Vs[cur][(16 + lo) * 72 + ks * 32 + quad * 8];
      o1 = __builtin_amdgcn_mfma_f32_16x16x32_bf16(v1, pfrag, o1, 0, 0, 0);
    }
    __builtin_amdgcn_s_setprio(0);
    // single barrier: staging of i+1 complete AND compute reads of buf cur
    // done before it is overwritten at iteration i+2
    __syncthreads();
    ebA = ebAn; ebB = ebBn;
  }
#undef EBLOAD

  // store partials (v_perm truncation pack):
  // o0[reg] = O^T[d=4*quad+reg][q=w*16+lo], o1: d+16
  int slot = (b * NHEADS + h) * 36 + blockIdx.x;
  u16* pw = po_o + (size_t)(kh * 576 + slot) * 2048 + w * 512;  // u16 units
  uint2 s0, s1;
  s0.x = pkbf(o0[0], o0[1]); s0.y = pkbf(o0[2], o0[3]);
  s1.x = pkbf(o1[0], o1[1]); s1.y = pkbf(o1[2], o1[3]);
  *(uint2*)(pw + lane * 4) = s0;
  *(uint2*)(pw + 256 + lane * 4) = s1;
  // lacc[r] all equal = full row-sum for q = lo (MFMA reduced across quads)
  if (quad == 0)
    po_l[(size_t)(kh * 576 + slot) * 64 + w * 16 + lo] = lacc[0];
}

// ---------------------------------------------------------------------------
// K3: fused reduce+out (R17-verified): phase 1 reduces the four split-K
// partials for this n-tile into a 32 KB swizzled LDS B-tile (normalized);
// phase 2 is the Wo GEMM with B-frags from LDS and A-frags inline from
// fp32 Wo. out[b][c][n] = x + gamma*(Wo ao)[c][n] + bo[c].
// grid (36, 4, 2), block 256.
__global__ __launch_bounds__(256) void out_kernel(
    const float* __restrict__ x, const float* __restrict__ Wo,
    const float* __restrict__ bo, const float* __restrict__ gp,
    const u16* __restrict__ po_o, const float* __restrict__ po_l,
    float* __restrict__ out) {
  int t = threadIdx.x;
  int w = t >> 6, lane = t & 63, lo = lane & 15, quad = lane >> 4;
  int qt_ = blockIdx.x;
  int c0 = blockIdx.y * 64;
  int b = blockIdx.z;
  float gamma = gp[0];

  __shared__ u16 Bt[16384];  // [64][256] bf16 in swz fragment order

  // phase 1: each wave reduces its 16-row n-subtile for all 8 heads
#pragma unroll 1
  for (int h = 0; h < NHEADS; ++h) {
    int slot = (b * NHEADS + h) * 36 + qt_;
    float s0[4] = {0.f, 0.f, 0.f, 0.f}, s1[4] = {0.f, 0.f, 0.f, 0.f};
    float lt = 0.f;
#pragma unroll
    for (int kh = 0; kh < 4; ++kh) {
      const u16* p = po_o + (size_t)(kh * 576 + slot) * 2048 + w * 512;
      ushort4 a0 = *(const ushort4*)(p + lane * 4);
      ushort4 a1 = *(const ushort4*)(p + 256 + lane * 4);
      s0[0] += bf2f(a0.x); s0[1] += bf2f(a0.y);
      s0[2] += bf2f(a0.z); s0[3] += bf2f(a0.w);
      s1[0] += bf2f(a1.x); s1[1] += bf2f(a1.y);
      s1[2] += bf2f(a1.z); s1[3] += bf2f(a1.w);
      lt += po_l[(size_t)(kh * 576 + slot) * 64 + w * 16 + lo];
    }
    float inv = 1.0f / lt;
    // LDS write at swz(nrow = w*16+lo, k = h*32 + quad*4 (+16))
    int base = w * 4096 + (h * 4 + (quad >> 1)) * 128 + lo * 8 + (quad & 1) * 4;
    ushort4 w0, w1;
    w0.x = f2bf(s0[0] * inv); w0.y = f2bf(s0[1] * inv);
    w0.z = f2bf(s0[2] * inv); w0.w = f2bf(s0[3] * inv);
    w1.x = f2bf(s1[0] * inv); w1.y = f2bf(s1[1] * inv);
    w1.z = f2bf(s1[2] * inv); w1.w = f2bf(s1[3] * inv);
    *(ushort4*)&Bt[base] = w0;
    *(ushort4*)&Bt[base + 256] = w1;  // k+16 -> (k>>3)+2 -> +2*128 u16
  }
  __syncthreads();

  // phase 2: GEMM, B-frags from LDS, A-frags inline from fp32 Wo
  const float* Ar = Wo + (size_t)(c0 + w * 16 + lo) * DMODEL + quad * 8;
  f32x4 acc[4] = {{0.f, 0.f, 0.f, 0.f}, {0.f, 0.f, 0.f, 0.f},
                  {0.f, 0.f, 0.f, 0.f}, {0.f, 0.f, 0.f, 0.f}};
#pragma unroll
  for (int k0 = 0; k0 < DMODEL; k0 += 32) {
    short8 af = ldA8(Ar + k0);
    int kblk = ((k0 >> 3) + quad) << 7;
#pragma unroll
    for (int nt = 0; nt < 4; ++nt) {
      short8 bf_ = *(const short8*)&Bt[nt * 4096 + kblk + lo * 8];
      acc[nt] = __builtin_amdgcn_mfma_f32_16x16x32_bf16(af, bf_, acc[nt], 0, 0, 0);
    }
  }

  int n0 = qt_ * 64;
#pragma unroll
  for (int reg = 0; reg < 4; ++reg) {
    int c = c0 + w * 16 + quad * 4 + reg;
    float bi = bo[c];
    const float* xs = x + (size_t)(b * DMODEL + c) * HW + n0 + lo;
    float* os = out + (size_t)(b * DMODEL + c) * HW + n0 + lo;
#pragma unroll
    for (int nt = 0; nt < 4; ++nt)
      os[nt * 16] = xs[nt * 16] + gamma * acc[nt][reg] + bi;
  }
}

// ---------------------------------------------------------------------------
extern "C" void kernel_launch(void* const* d_in, const int* in_sizes, int n_in,
                              void* d_out, int out_size, void* d_ws,
                              size_t ws_size, hipStream_t stream) {
  const float* x   = (const float*)d_in[0];
  const float* Wq  = (const float*)d_in[1];
  const float* bq  = (const float*)d_in[2];
  const float* Wk  = (const float*)d_in[3];
  const float* bk  = (const float*)d_in[4];
  const float* Wv  = (const float*)d_in[5];
  const float* bv  = (const float*)d_in[6];
  const float* Wo  = (const float*)d_in[7];
  const float* bo  = (const float*)d_in[8];
  const float* lam = (const float*)d_in[9];
  const float* gam = (const float*)d_in[10];

  // ws layout (bytes):
  //   qt    bf16 [2920448, 5279744)
  //   ktb   bf16 [5279744, 7639040)
  //   vb    bf16 [7639040, 9998336)
  //   et    bf16 [9998336, 10241536)  compact bias: 475 tiles * 256 * 2B
  //   po_o  bf16 [20615168, 30052352) split-K(4) partial O
  //   po_l  f32  [30052352, 30642176) split-K(4) partial rowsums
  char* wsb = (char*)d_ws;
  u16* qt  = (u16*)(wsb + 2920448);
  u16* ktb = (u16*)(wsb + 5279744);
  u16* vb  = (u16*)(wsb + 7639040);
  u16* et  = (u16*)(wsb + 9998336);
  u16* po_o = (u16*)(wsb + 20615168);
  float* po_l = (float*)(wsb + 30052352);
  float* out = (float*)d_out;

  qkv_kernel<<<dim3(924), 256, 0, stream>>>(x, Wq, Wk, Wv, bq, bk, bv, lam,
                                            qt, ktb, vb, et);
  attn_kernel<<<dim3(36, 32, BATCH), 256, 0, stream>>>(qt, ktb, vb, et,
                                                       po_o, po_l);
  out_kernel<<<dim3(36, 4, BATCH), 256, 0, stream>>>(x, Wo, bo, gam,
                                                     po_o, po_l, out);
}

// Round 7
// 123.739 us; speedup vs baseline: 1.0303x; 1.0303x over previous
//
#include <hip/hip_runtime.h>

// Problem constants (B=2, C=256, H=W=48, d_model=256, 8 heads, d_k=32)
// Inputs/outputs fp32. Internals bf16; all matmuls + attention on MFMA.
// Wb / xt in MFMA-fragment-order swizzle:
//   addr(row,k) = (row>>4)*4096 + (k>>3)*128 + (row&15)*8 + (k&7)
// R16: distance bias exploits translation invariance: 48=3*16 so a 16-q-tile
// never crosses a y-row -> bias tile determined by (dy,row-phase-delta):
// 475 unique 16x16 tiles (243 KB) instead of 20736 (10.6 MB).
// Bias folded into S-MFMA C-in; softmax in exp2 domain (Q and table
// pre-scaled by log2(e)); row-sums via ones-fragment MFMA.
// reduce fused into out (split-K partials reduced into LDS B-tile).
// (R22 = R16 resubmitted verbatim: best-measured config at 124.73us;
// R17/R21 restructures measured worse, attn rewrites failed — restoring
// the empirical optimum.)
#define HW 2304
#define SW 48
#define DMODEL 256
#define NHEADS 8
#define DK 32
#define BATCH 2

typedef unsigned short u16;
typedef __attribute__((ext_vector_type(8))) short short8;
typedef __attribute__((ext_vector_type(4))) float f32x4;

__device__ __forceinline__ float bf2f(u16 v) {
  union { unsigned int u; float f; } c; c.u = ((unsigned int)v) << 16; return c.f;
}
__device__ __forceinline__ float lo2f(unsigned int u) {
  union { unsigned int u; float f; } c; c.u = u << 16; return c.f;
}
__device__ __forceinline__ float hi2f(unsigned int u) {
  union { unsigned int u; float f; } c; c.u = u & 0xffff0000u; return c.f;
}
__device__ __forceinline__ u16 f2bf(float f) {
  union { unsigned int u; float f; } c; c.f = f;
  unsigned int u = c.u;
  unsigned int r = (u + 0x7FFFu + ((u >> 16) & 1u)) >> 16;
  return (u16)r;
}
// pack two floats -> two bf16 (TRUNCATION) in one v_perm_b32
__device__ __forceinline__ unsigned int pkbf(float a, float b) {
  union { float f; unsigned int u; } ca, cb;
  ca.f = a; cb.f = b;
  return __builtin_amdgcn_perm(ca.u, cb.u, 0x03020706u);
}
// native exp2 (P = exp2(S') with S' pre-scaled by log2 e == exp(S))
__device__ __forceinline__ float ex2(float x) {
#if __has_builtin(__builtin_amdgcn_exp2f)
  return __builtin_amdgcn_exp2f(x);
#else
  return __expf(x * 0.6931471805599453f);
#endif
}
// exact floor(n/48) for n in [0, 2304): magic 87382 = (2^22+32)/48
__device__ __forceinline__ int div48(int n) { return (n * 87382) >> 22; }
// exact floor(n/3) for n < 512
__device__ __forceinline__ int div3(int n) { return (n * 171) >> 9; }
// fragment-order swizzle for a [rows][256] bf16 matrix
__device__ __forceinline__ int swz(int row, int k) {
  return ((row >> 4) << 12) + ((k >> 3) << 7) + ((row & 15) << 3) + (k & 7);
}

#define LOG2E 1.4426950408889634f

// ---------------------------------------------------------------------------
// fused prep: [0,288) transpose x -> xt (swizzled) ; [288,544) W fp32->bf16
// swizzled [q|k|v|o] ; [544,604) compact bias table (475 tiles x 256).
// Bias tile index = (dy+47)*5 + (pq-pm+2); entry = q_local*16 + m_local;
// value = lam*log2e*exp(-sqrt(dy^2 + ((pq-pm)*16 + q_local - m_local)^2)).
// grid 604, block 256.
__global__ __launch_bounds__(256) void prep_kernel(
    const float* __restrict__ x,
    const float* __restrict__ Wq, const float* __restrict__ Wk,
    const float* __restrict__ Wv, const float* __restrict__ Wo,
    const float* __restrict__ lam_p,
    u16* __restrict__ xt, u16* __restrict__ Wb, u16* __restrict__ et) {
  int bid = blockIdx.x;
  int t = threadIdx.x;
  if (bid < 288) {
    int b = bid / 144, r = bid % 144;
    int c0 = (r / 36) * 64, n0 = (r % 36) * 64;
    __shared__ u16 sh[64][72];  // [n][c]
#pragma unroll
    for (int p = 0; p < 4; ++p) {
      int row = (t >> 4) + p * 16;   // c
      int col4 = (t & 15) * 4;       // n
      float4 v = *(const float4*)(x + (size_t)(b * DMODEL + c0 + row) * HW +
                                  n0 + col4);
      sh[col4 + 0][row] = f2bf(v.x);
      sh[col4 + 1][row] = f2bf(v.y);
      sh[col4 + 2][row] = f2bf(v.z);
      sh[col4 + 3][row] = f2bf(v.w);
    }
    __syncthreads();
    u16* xtb = xt + (size_t)b * HW * DMODEL;
#pragma unroll
    for (int q = 0; q < 2; ++q) {
      int nrow = t >> 2;
      int c8 = (t & 3) * 8 + q * 32;
      *(uint4*)(xtb + swz(n0 + nrow, c0 + c8)) = *(const uint4*)&sh[nrow][c8];
    }
  } else if (bid < 544) {
    int idx = (bid - 288) * 1024 + t * 4;
    int which = idx >> 16, off = idx & 65535;
    int m = off >> 8, k = off & 255;
    const float* src = (which == 0) ? Wq : (which == 1) ? Wk
                       : (which == 2) ? Wv : Wo;
    float4 v = *(const float4*)(src + off);
    ushort4 ov;
    ov.x = f2bf(v.x); ov.y = f2bf(v.y); ov.z = f2bf(v.z); ov.w = f2bf(v.w);
    *(ushort4*)(Wb + which * 65536 + swz(m, k)) = ov;
  } else {
    int id = (bid - 544) * 256 + t;
    if (id < 15200) {                // 475 tiles * 256 / 8
      int flat = id * 8;
      int tile = flat >> 8;          // 0..474
      int within = flat & 255;
      int a = within >> 4;           // q_local
      int b0 = within & 15;          // m_local base (0 or 8)
      int dyi = (tile * 205) >> 10;  // tile/5, exact for tile<1024
      int dp = tile - dyi * 5;       // 0..4
      float dy = (float)(dyi - 47);
      float dy2 = dy * dy;
      int dxb = (dp - 2) * 16 + a - b0;
      float lam = lam_p[0] * LOG2E;
      u16 o[8];
#pragma unroll
      for (int j = 0; j < 8; ++j) {
        float dx = (float)(dxb - j);
        o[j] = f2bf(lam * __expf(-sqrtf(dy2 + dx * dx)));
      }
      *(uint4*)(et + flat) = *(const uint4*)o;
    }
  }
}

// ---------------------------------------------------------------------------
// QKV projection, LDS-free MFMA GEMM with swizzled frag loads.
// Q scaled by (1/sqrt(dk))*log2(e) so attention runs in exp2 domain.
// grid (36, 12, 2), block 256.
__global__ __launch_bounds__(256) void qkv_kernel(
    const u16* __restrict__ Wb, const u16* __restrict__ xt,
    const float* __restrict__ bq, const float* __restrict__ bk,
    const float* __restrict__ bv,
    u16* __restrict__ qt, u16* __restrict__ ktb, u16* __restrict__ vb) {
  int t = threadIdx.x;
  int w = t >> 6, lane = t & 63, lo = lane & 15, quad = lane >> 4;
  int n0 = blockIdx.x * 64;
  int mb = blockIdx.y, b = blockIdx.z;
  int which = mb >> 2;
  int mrel0 = (mb & 3) * 64;
  const u16* A = Wb + which * 65536 + ((mrel0 + w * 16) >> 4) * 4096 + lo * 8;
  const float* bias = (which == 0) ? bq : (which == 1) ? bk : bv;
  const u16* Bx = xt + (size_t)b * HW * DMODEL + lo * 8;

  f32x4 acc[4] = {{0.f, 0.f, 0.f, 0.f}, {0.f, 0.f, 0.f, 0.f},
                  {0.f, 0.f, 0.f, 0.f}, {0.f, 0.f, 0.f, 0.f}};
#pragma unroll
  for (int k0 = 0; k0 < DMODEL; k0 += 32) {
    int kblk = ((k0 >> 3) + quad) << 7;
    short8 af = *(const short8*)(A + kblk);
#pragma unroll
    for (int nt = 0; nt < 4; ++nt) {
      short8 bf_ = *(const short8*)(Bx + ((n0 + nt * 16) >> 4) * 4096 + kblk);
      acc[nt] = __builtin_amdgcn_mfma_f32_16x16x32_bf16(af, bf_, acc[nt], 0, 0, 0);
    }
  }

  int mbase = mrel0 + w * 16 + quad * 4;
  if (which == 2) {
#pragma unroll
    for (int reg = 0; reg < 4; ++reg) {
      int mrel = mbase + reg;
      float bi = bias[mrel];
      u16* dst = vb + (size_t)(b * DMODEL + mrel) * HW + n0 + lo;
#pragma unroll
      for (int nt = 0; nt < 4; ++nt) dst[nt * 16] = f2bf(acc[nt][reg] + bi);
    }
  } else {
    float sc = (which == 0) ? (0.17677669529663687f * LOG2E) : 1.0f;
    int h = mbase >> 5, d0 = mbase & 31;
    u16* base = ((which == 0) ? qt : ktb) + (size_t)(b * NHEADS + h) * HW * DK;
    float bi[4], dv[4];
    bool usecos[4], usey[4];
#pragma unroll
    for (int reg = 0; reg < 4; ++reg) {
      int mrel = mbase + reg;
      bi[reg] = bias[mrel];
      int oo = mrel & 127;
      dv[reg] = __expf(-0.07195578415606394f * (float)(oo & ~1));
      usecos[reg] = (oo & 1);
      usey[reg] = (mrel >= 128);
    }
#pragma unroll
    for (int nt = 0; nt < 4; ++nt) {
      int n = n0 + nt * 16 + lo;
      int yy = div48(n), xx = n - yy * SW;
      ushort4 ov;
      float vals[4];
#pragma unroll
      for (int reg = 0; reg < 4; ++reg) {
        float tv = (usey[reg] ? (float)yy : (float)xx) * dv[reg];
        float pe = usecos[reg] ? __cosf(tv) : __sinf(tv);
        vals[reg] = (acc[nt][reg] + bi[reg] + pe) * sc;
      }
      ov.x = f2bf(vals[0]); ov.y = f2bf(vals[1]);
      ov.z = f2bf(vals[2]); ov.w = f2bf(vals[3]);
      *(ushort4*)(base + (size_t)n * DK + d0) = ov;
    }
  }
}

// ---------------------------------------------------------------------------
// MFMA flash attention, S^T + register-resident P, split-K(4), double-buffered
// K/V staging. Bias from compact table as S-MFMA C-in; P = v_exp_f32
// (exp2 domain); row-sums via ones-fragment MFMA (no VALU adds / shuffles).
// grid (36, 32, 2): y = h*4+kh. block 256.
__global__ __launch_bounds__(256) void attn_kernel(
    const u16* __restrict__ qt, const u16* __restrict__ ktb,
    const u16* __restrict__ vb, const u16* __restrict__ et,
    u16* __restrict__ po_o, float* __restrict__ po_l) {
  int t = threadIdx.x;
  int w = t >> 6;
  int lane = t & 63;
  int lo = lane & 15, quad = lane >> 4;
  int n0 = blockIdx.x * 64;
  int h = blockIdx.y >> 2, kh = blockIdx.y & 3;
  int b = blockIdx.z;

  __shared__ u16 Ks[2][64 * 40];  // ping-pong permuted-row K tiles
  __shared__ u16 Vs[2][32 * 72];  // ping-pong V^T tiles [d][m]

  const u16* qtg = qt + (size_t)(b * NHEADS + h) * HW * DK;
  const u16* ktg = ktb + (size_t)(b * NHEADS + h) * HW * DK;
  const u16* vbg = vb + (size_t)(b * DMODEL + h * DK) * HW;

  short8 qf = *(const short8*)(qtg + (size_t)(n0 + w * 16 + lo) * DK + quad * 8);

  // staging source-key for this thread's LDS row (permutation applied here)
  int srow = t >> 2;                 // LDS row 0..63
  int sks = srow >> 5, srr = srow & 31;
  int sv = (srr < 16) ? (8 * (srr >> 2) + (srr & 3))
                      : (8 * ((srr - 16) >> 2) + 4 + ((srr - 16) & 3));
  int skey = sks * 32 + sv;          // key offset within 64-tile
  int sc8 = (t & 3) * 8;
  int vdd = t >> 3, vmo = (t & 7) * 8;

  // compact bias addressing: tile = qcode - (tm + 2*floor(tm/3))
  int tq = (n0 >> 4) + w;
  int qh = quad >> 1;
  int yqt = div3(tq);
  int qcode = tq + 2 * yqt + 237;    // (yq+47)*5 + pq + 2  (minus m-code)
  const u16* etb = et + lo * 16 + (quad & 1) * 8;

  union { unsigned int u[4]; short8 s; } onesu;
  onesu.u[0] = onesu.u[1] = onesu.u[2] = onesu.u[3] = 0x3F803F80u;  // bf16 1.0
  const short8 onesf = onesu.s;

  f32x4 o0 = {0.f, 0.f, 0.f, 0.f}, o1 = {0.f, 0.f, 0.f, 0.f};
  f32x4 lacc = {0.f, 0.f, 0.f, 0.f};

  const int kt0 = kh * 9;
  // prologue: stage tile kt0 into buffer 0
  {
    int m0 = kt0 * 64;
    *(uint4*)&Ks[0][srow * 40 + sc8] =
        *(const uint4*)(ktg + (size_t)(m0 + skey) * DK + sc8);
    *(uint4*)&Vs[0][vdd * 72 + vmo] =
        *(const uint4*)(vbg + (size_t)vdd * HW + m0 + vmo);
  }
  __syncthreads();

  for (int i = 0; i < 9; ++i) {
    int cur = i & 1;
    // stage tile i+1 into the other buffer (no barrier needed: distinct buf)
    if (i + 1 < 9) {
      int m1 = (kt0 + i + 1) * 64;
      *(uint4*)&Ks[cur ^ 1][srow * 40 + sc8] =
          *(const uint4*)(ktg + (size_t)(m1 + skey) * DK + sc8);
      *(uint4*)&Vs[cur ^ 1][vdd * 72 + vmo] =
          *(const uint4*)(vbg + (size_t)vdd * HW + m1 + vmo);
    }

    // bias tiles for this 64-key slab from the 475-tile compact table
    int tm0 = (kt0 + i) * 4 + qh;
    int tm1 = tm0 + 2;
    int ym0 = div3(tm0), ym1 = div3(tm1);
    uint4 eb0 = *(const uint4*)(etb + (size_t)(qcode - tm0 - 2 * ym0) * 256);
    uint4 eb1 = *(const uint4*)(etb + (size_t)(qcode - tm1 - 2 * ym1) * 256);

#pragma unroll
    for (int ks = 0; ks < 2; ++ks) {
      uint4 ebv = ks ? eb1 : eb0;
      // S^T: A = permuted K rows, B = Q, C-in = bias (log2e domain)
      short8 kfA = *(const short8*)&Ks[cur][(ks * 32 + lo) * 40 + quad * 8];
      short8 kfB = *(const short8*)&Ks[cur][(ks * 32 + 16 + lo) * 40 + quad * 8];
      f32x4 zA = {lo2f(ebv.x), hi2f(ebv.x), lo2f(ebv.y), hi2f(ebv.y)};
      f32x4 zB = {lo2f(ebv.z), hi2f(ebv.z), lo2f(ebv.w), hi2f(ebv.w)};
      f32x4 sA = __builtin_amdgcn_mfma_f32_16x16x32_bf16(kfA, qf, zA, 0, 0, 0);
      f32x4 sB = __builtin_amdgcn_mfma_f32_16x16x32_bf16(kfB, qf, zB, 0, 0, 0);
      // P = exp2(S') : lane's m = ks*32 + 8*quad + {0..7}, q = lo
      float p0 = ex2(sA[0]), p1 = ex2(sA[1]), p2 = ex2(sA[2]), p3 = ex2(sA[3]);
      float p4 = ex2(sB[0]), p5 = ex2(sB[1]), p6 = ex2(sB[2]), p7 = ex2(sB[3]);
      // pack into PV B-fragment via v_perm truncation (1 op per 2 values)
      unsigned int pk32[4] = {pkbf(p0, p1), pkbf(p2, p3),
                              pkbf(p4, p5), pkbf(p6, p7)};
      short8 pfrag = *(const short8*)pk32;
      // row-sums: ones-fragment MFMA sums P over all 32 keys (cross-quad too)
      lacc = __builtin_amdgcn_mfma_f32_16x16x32_bf16(onesf, pfrag, lacc, 0, 0, 0);
      // O^T += V^T P^T : A = V^T rows d, B = P (q cols)
      short8 v0 = *(const short8*)&Vs[cur][lo * 72 + ks * 32 + quad * 8];
      o0 = __builtin_amdgcn_mfma_f32_16x16x32_bf16(v0, pfrag, o0, 0, 0, 0);
      short8 v1 = *(const short8*)&Vs[cur][(16 + lo) * 72 + ks * 32 + quad * 8];
      o1 = __builtin_amdgcn_mfma_f32_16x16x32_bf16(v1, pfrag, o1, 0, 0, 0);
    }
    // single barrier: staging of i+1 complete AND compute reads of buf cur
    // done before it is overwritten at iteration i+2
    __syncthreads();
  }

  // store partials (v_perm truncation pack):
  // o0[reg] = O^T[d=4*quad+reg][q=w*16+lo], o1: d+16
  int slot = (b * NHEADS + h) * 36 + blockIdx.x;
  u16* pw = po_o + (size_t)(kh * 576 + slot) * 2048 + w * 512;  // u16 units
  uint2 s0, s1;
  s0.x = pkbf(o0[0], o0[1]); s0.y = pkbf(o0[2], o0[3]);
  s1.x = pkbf(o1[0], o1[1]); s1.y = pkbf(o1[2], o1[3]);
  *(uint2*)(pw + lane * 4) = s0;
  *(uint2*)(pw + 256 + lane * 4) = s1;
  // lacc[r] all equal = full row-sum for q = lo (MFMA reduced across quads)
  if (quad == 0)
    po_l[(size_t)(kh * 576 + slot) * 64 + w * 16 + lo] = lacc[0];
}

// ---------------------------------------------------------------------------
// fused reduce+out: phase 1 reduces the four split-K partials for this n-tile
// into a 32 KB swizzled LDS B-tile (normalized); phase 2 is the Wo GEMM with
// B-frags from LDS. out[b][c][n] = x + gamma*(Wo ao)[c][n] + bo[c].
// grid (36, 4, 2), block 256.
__global__ __launch_bounds__(256) void out_kernel(
    const float* __restrict__ x, const u16* __restrict__ Wob,
    const float* __restrict__ bo, const float* __restrict__ gp,
    const u16* __restrict__ po_o, const float* __restrict__ po_l,
    float* __restrict__ out) {
  int t = threadIdx.x;
  int w = t >> 6, lane = t & 63, lo = lane & 15, quad = lane >> 4;
  int qt_ = blockIdx.x;
  int c0 = blockIdx.y * 64;
  int b = blockIdx.z;
  float gamma = gp[0];

  __shared__ u16 Bt[16384];  // [64][256] bf16 in swz fragment order

  // phase 1: each wave reduces its 16-row n-subtile for all 8 heads
#pragma unroll 1
  for (int h = 0; h < NHEADS; ++h) {
    int slot = (b * NHEADS + h) * 36 + qt_;
    float s0[4] = {0.f, 0.f, 0.f, 0.f}, s1[4] = {0.f, 0.f, 0.f, 0.f};
    float lt = 0.f;
#pragma unroll
    for (int kh = 0; kh < 4; ++kh) {
      const u16* p = po_o + (size_t)(kh * 576 + slot) * 2048 + w * 512;
      ushort4 a0 = *(const ushort4*)(p + lane * 4);
      ushort4 a1 = *(const ushort4*)(p + 256 + lane * 4);
      s0[0] += bf2f(a0.x); s0[1] += bf2f(a0.y);
      s0[2] += bf2f(a0.z); s0[3] += bf2f(a0.w);
      s1[0] += bf2f(a1.x); s1[1] += bf2f(a1.y);
      s1[2] += bf2f(a1.z); s1[3] += bf2f(a1.w);
      lt += po_l[(size_t)(kh * 576 + slot) * 64 + w * 16 + lo];
    }
    float inv = 1.0f / lt;
    // LDS write at swz(nrow = w*16+lo, k = h*32 + quad*4 (+16))
    int base = w * 4096 + (h * 4 + (quad >> 1)) * 128 + lo * 8 + (quad & 1) * 4;
    ushort4 w0, w1;
    w0.x = f2bf(s0[0] * inv); w0.y = f2bf(s0[1] * inv);
    w0.z = f2bf(s0[2] * inv); w0.w = f2bf(s0[3] * inv);
    w1.x = f2bf(s1[0] * inv); w1.y = f2bf(s1[1] * inv);
    w1.z = f2bf(s1[2] * inv); w1.w = f2bf(s1[3] * inv);
    *(ushort4*)&Bt[base] = w0;
    *(ushort4*)&Bt[base + 256] = w1;  // k+16 -> (k>>3)+2 -> +2*128 u16
  }
  __syncthreads();

  // phase 2: GEMM, B-frags from LDS
  const u16* A = Wob + ((c0 + w * 16) >> 4) * 4096 + lo * 8;
  f32x4 acc[4] = {{0.f, 0.f, 0.f, 0.f}, {0.f, 0.f, 0.f, 0.f},
                  {0.f, 0.f, 0.f, 0.f}, {0.f, 0.f, 0.f, 0.f}};
#pragma unroll
  for (int k0 = 0; k0 < DMODEL; k0 += 32) {
    int kblk = ((k0 >> 3) + quad) << 7;
    short8 af = *(const short8*)(A + kblk);
#pragma unroll
    for (int nt = 0; nt < 4; ++nt) {
      short8 bf_ = *(const short8*)&Bt[nt * 4096 + kblk + lo * 8];
      acc[nt] = __builtin_amdgcn_mfma_f32_16x16x32_bf16(af, bf_, acc[nt], 0, 0, 0);
    }
  }

  int n0 = qt_ * 64;
#pragma unroll
  for (int reg = 0; reg < 4; ++reg) {
    int c = c0 + w * 16 + quad * 4 + reg;
    float bi = bo[c];
    const float* xs = x + (size_t)(b * DMODEL + c) * HW + n0 + lo;
    float* os = out + (size_t)(b * DMODEL + c) * HW + n0 + lo;
#pragma unroll
    for (int nt = 0; nt < 4; ++nt)
      os[nt * 16] = xs[nt * 16] + gamma * acc[nt][reg] + bi;
  }
}

// ---------------------------------------------------------------------------
extern "C" void kernel_launch(void* const* d_in, const int* in_sizes, int n_in,
                              void* d_out, int out_size, void* d_ws,
                              size_t ws_size, hipStream_t stream) {
  const float* x   = (const float*)d_in[0];
  const float* Wq  = (const float*)d_in[1];
  const float* bq  = (const float*)d_in[2];
  const float* Wk  = (const float*)d_in[3];
  const float* bk  = (const float*)d_in[4];
  const float* Wv  = (const float*)d_in[5];
  const float* bv  = (const float*)d_in[6];
  const float* Wo  = (const float*)d_in[7];
  const float* bo  = (const float*)d_in[8];
  const float* lam = (const float*)d_in[9];
  const float* gam = (const float*)d_in[10];

  // ws layout (bytes):
  //   (unused)   [0, 36864)
  //   Wb    bf16 [36864, 561152)      4*65536*2, [q|k|v|o], swizzled
  //   xt    bf16 [561152, 2920448)    swizzled
  //   qt    bf16 [2920448, 5279744)
  //   ktb   bf16 [5279744, 7639040)
  //   vb    bf16 [7639040, 9998336)
  //   et    bf16 [9998336, 10241536)  compact bias: 475 tiles * 256 * 2B
  //   po_o  bf16 [20615168, 30052352) split-K(4) partial O
  //   po_l  f32  [30052352, 30642176) split-K(4) partial rowsums
  char* wsb = (char*)d_ws;
  u16* Wb  = (u16*)(wsb + 36864);
  u16* xt  = (u16*)(wsb + 561152);
  u16* qt  = (u16*)(wsb + 2920448);
  u16* ktb = (u16*)(wsb + 5279744);
  u16* vb  = (u16*)(wsb + 7639040);
  u16* et  = (u16*)(wsb + 9998336);
  u16* po_o = (u16*)(wsb + 20615168);
  float* po_l = (float*)(wsb + 30052352);
  float* out = (float*)d_out;

  prep_kernel<<<dim3(604), 256, 0, stream>>>(x, Wq, Wk, Wv, Wo, lam,
                                             xt, Wb, et);
  qkv_kernel<<<dim3(36, 12, BATCH), 256, 0, stream>>>(Wb, xt, bq, bk, bv,
                                                      qt, ktb, vb);
  attn_kernel<<<dim3(36, 32, BATCH), 256, 0, stream>>>(qt, ktb, vb, et,
                                                       po_o, po_l);
  out_kernel<<<dim3(36, 4, BATCH), 256, 0, stream>>>(x, Wb + 3 * 65536, bo, gam,
                                                     po_o, po_l, out);
}